// Round 12
// baseline (113.769 us; speedup 1.0000x reference)
//
#include <hip/hip_runtime.h>
#include <math.h>

#define NCLS 676
#define NEG_SENTINEL -3.0e38f  // finite stand-in for -inf (checker: inf-inf=nan)
#define LN2F 0.6931471805599453f
#define JPAD 768     // padded j-axis of weight tables (R2: 768 is conflict-optimal)
#define RS 256       // aD/bD diag-row stride, i-indexed (R4): [d*RS + 255 - i]
#define QIP_OFF 692  // qip base (16-float front guard after pw)
#define WSE_OFF (QIP_OFF + JPAD)             // 1460
#define CTL_PROG 20692                       // producer progress (int)
#define CTL_CONS 20693                       // consumer progress (int)
#define SLOT_OFF 20696                       // 2 slots x 12 floats, 16B aligned
#define SHM_TOT 20720                        // 82.9 KB -> 1 block/CU
#define MAGIC 0x13579BDFu
#define NSLICE 8     // sliced S copies: 8x fewer atomics per address

__device__ __forceinline__ float dpp_shr1(float x) {  // lane n <- n-1, lane0 0
  return __int_as_float(
      __builtin_amdgcn_update_dpp(0, __float_as_int(x), 0x138, 0xF, 0xF, false));
}
__device__ __forceinline__ float dpp_shl1(float x) {  // lane n <- n+1, lane63 0
  return __int_as_float(
      __builtin_amdgcn_update_dpp(0, __float_as_int(x), 0x130, 0xF, 0xF, false));
}
__device__ __forceinline__ int dpp_shr1_i(int x) {
  return __builtin_amdgcn_update_dpp(0, x, 0x138, 0xF, 0xF, false);
}
__device__ __forceinline__ int dpp_shl1_i(int x) {
  return __builtin_amdgcn_update_dpp(0, x, 0x130, 0xF, 0xF, false);
}
__device__ __forceinline__ float pow2c(int d) {  // exact 2^d, clamped
  d = min(max(d, -126), 126);
  return __int_as_float((d + 127) << 23);
}

// R12: ADDRSPACE FIX + LOAD-COST PROBE. R11 closed the environment theories
// (burner deletion null: k_dp 40.28 ~ R9/R10; conflicts 11830->2730 no time
// effect). ~1300cy/PROC @2.1GHz vs ~300-600cy models, invariant to all
// code-level changes. New suspect: table loads went through generic
// pointers held in a private array (const float* rowp[k]) -- if addrspace
// inference fails through the alloca, the 18 loads/PROC are FLAT loads
// (vmcnt+lgkmcnt, TA/TD path, ~150-200cy, poorly pipelined), not ds_read.
// (1) Fix: all table access now direct shm[int_offset] -- addrspace(3)
//     trivially inferable. Semantics identical.
// (2) Probe: alpha-consumer runs 128 LOAD-only iterations (2x the DP's 64)
//     with asm sinks after its DP loop; its time adds to k_dp.
// Decision matrix for k_dp: 24-32us => fix worked (drop probe, ship);
// 44-48us => loads always cheap, ablate u-loop next; >=75us => loads
// expensive + fix null, cut load count structurally.
__global__ __launch_bounds__(256, 1) void k_dp(const int* __restrict__ ar,
                                               const int* __restrict__ en,
                                               const float* __restrict__ wts,
                                               float* __restrict__ aD,
                                               float* __restrict__ bD,
                                               int* __restrict__ aEb,
                                               int* __restrict__ bEb,
                                               float* __restrict__ S,
                                               unsigned* __restrict__ flags) {
  const int tid = threadIdx.x;
  __shared__ alignas(16) float shm[SHM_TOT];

  // ---------------- DP blocks 0 (alpha) / 1 (beta) ----------------------
  float* pw = shm;  // exp(weights), 676
  int* progp = (int*)(shm + CTL_PROG);
  int* consp = (int*)(shm + CTL_CONS);
  for (int c = tid; c < NCLS; c += 256) pw[c] = __expf(wts[c]);
  {  // zero guards + tables + ctl area (16B aligned at 676*4)
    float4* z = (float4*)(shm + NCLS);
    const int nz = (SHM_TOT - NCLS) / 4;
    for (int t = tid; t < nz; t += 256) z[t] = make_float4(0.f, 0.f, 0.f, 0.f);
  }
  if (tid == 0) { *progp = 0; *consp = 0; }
  if (blockIdx.x == 0) {
    for (int c = tid; c < NSLICE * NCLS; c += 256) S[c] = 0.f;
    if (tid == 0)
      __hip_atomic_store(&flags[2], 0u, __ATOMIC_RELAXED,
                         __HIP_MEMORY_SCOPE_AGENT);  // k_red ticket
  }
  __syncthreads();
  {
    int j = tid;  // 256 threads: one column each
    int ee = en[j];
    shm[QIP_OFF + 255 + j] = pw[26 + ee];
#pragma unroll
    for (int a = 0; a < 25; ++a)
      shm[WSE_OFF + a * JPAD + 255 + j] = pw[51 + 25 * a + ee];
  }
  __syncthreads();
  const int wid = tid >> 6;
  const int lane = tid & 63;
  if (wid >= 2) return;  // waves 2-3 done after table build

  const int i0 = 2 * lane + 128 * wid;  // this lane's 2 rows: i0, i0+1
  float wdl[2];
  int roff[2];  // integer offsets into shm (addrspace-safe, no generic ptrs)
#pragma unroll
  for (int k = 0; k < 2; ++k) {
    int a = ar[i0 + k];
    wdl[k] = pw[1 + a];
    roff[k] = WSE_OFF + a * JPAD;
  }
  float P1[2] = {0.f, 0.f};
  float P2[2] = {0.f, 0.f};
  int e1 = 0;

// 12-float window loads via direct shm indexing (8B-aligned: offsets even)
#define LOAD_A2(EB)                                                        \
  {                                                                        \
    _Pragma("unroll") for (int k = 0; k < 2; ++k) {                        \
      const int bo = roff[k] + (EB);                                       \
      float2 va = *(const float2*)&shm[bo];                                \
      float2 vb = *(const float2*)&shm[bo + 2];                            \
      float2 vc = *(const float2*)&shm[bo + 4];                            \
      float2 vd = *(const float2*)&shm[bo + 6];                            \
      float2 ve = *(const float2*)&shm[bo + 8];                            \
      float2 vf = *(const float2*)&shm[bo + 10];                           \
      W[k][0] = va.x; W[k][1] = va.y; W[k][2] = vb.x; W[k][3] = vb.y;      \
      W[k][4] = vc.x; W[k][5] = vc.y; W[k][6] = vd.x; W[k][7] = vd.y;      \
      W[k][8] = ve.x; W[k][9] = ve.y; W[k][10] = vf.x; W[k][11] = vf.y;    \
    }                                                                      \
    const int qo = QIP_OFF + (EB);                                         \
    float2 qa = *(const float2*)&shm[qo];                                  \
    float2 qb = *(const float2*)&shm[qo + 2];                              \
    float2 qc = *(const float2*)&shm[qo + 4];                              \
    float2 qd = *(const float2*)&shm[qo + 6];                              \
    float2 qe = *(const float2*)&shm[qo + 8];                              \
    float2 qf = *(const float2*)&shm[qo + 10];                             \
    Q[0] = qa.x; Q[1] = qa.y; Q[2] = qb.x; Q[3] = qb.y; Q[4] = qc.x;       \
    Q[5] = qc.y; Q[6] = qd.x; Q[7] = qd.y; Q[8] = qe.x; Q[9] = qe.y;       \
    Q[10] = qf.x; Q[11] = qf.y;                                            \
  }

// 16-float window loads (beta), direct shm indexing
#define LOAD_B2(EB)                                                        \
  {                                                                        \
    _Pragma("unroll") for (int k = 0; k < 2; ++k) {                        \
      const int bo = roff[k] + (EB);                                       \
      float2 va = *(const float2*)&shm[bo];                                \
      float2 vb = *(const float2*)&shm[bo + 2];                            \
      float2 vc = *(const float2*)&shm[bo + 4];                            \
      float2 vd = *(const float2*)&shm[bo + 6];                            \
      float2 ve = *(const float2*)&shm[bo + 8];                            \
      float2 vf = *(const float2*)&shm[bo + 10];                           \
      float2 vg = *(const float2*)&shm[bo + 12];                           \
      float2 vh = *(const float2*)&shm[bo + 14];                           \
      W[k][0] = va.x; W[k][1] = va.y; W[k][2] = vb.x; W[k][3] = vb.y;      \
      W[k][4] = vc.x; W[k][5] = vc.y; W[k][6] = vd.x; W[k][7] = vd.y;      \
      W[k][8] = ve.x; W[k][9] = ve.y; W[k][10] = vf.x; W[k][11] = vf.y;    \
      W[k][12] = vg.x; W[k][13] = vg.y; W[k][14] = vh.x; W[k][15] = vh.y;  \
    }                                                                      \
    const int qo = QIP_OFF + (EB);                                         \
    float2 qa = *(const float2*)&shm[qo];                                  \
    float2 qb = *(const float2*)&shm[qo + 2];                              \
    float2 qc = *(const float2*)&shm[qo + 4];                              \
    float2 qd = *(const float2*)&shm[qo + 6];                              \
    float2 qe = *(const float2*)&shm[qo + 8];                              \
    float2 qf = *(const float2*)&shm[qo + 10];                             \
    float2 qg = *(const float2*)&shm[qo + 12];                             \
    float2 qh = *(const float2*)&shm[qo + 14];                             \
    Q[0] = qa.x; Q[1] = qa.y; Q[2] = qb.x; Q[3] = qb.y; Q[4] = qc.x;       \
    Q[5] = qc.y; Q[6] = qd.x; Q[7] = qd.y; Q[8] = qe.x; Q[9] = qe.y;       \
    Q[10] = qf.x; Q[11] = qf.y; Q[12] = qg.x; Q[13] = qg.y; Q[14] = qh.x;  \
    Q[15] = qh.y;                                                          \
  }

  if (blockIdx.x == 0) {
    if (wid == 0) {
      // ---------- ALPHA PRODUCER: rows 0..127; emits row 127 ----------
      if (lane == 0) { P1[0] = 1.f; aD[255] = 1.f; }  // A(0,0)
      int e0 = 252 - i0;
      float* sp = aD + RS + 254 - i0;
      int* ep = aEb + i0;
      float W[2][12], Q[12];
      LOAD_A2(e0);
      for (int p = 0; p < 64; ++p) {
        const int e1st = e1;
        int t1e = dpp_shr1_i(e1);
        float f1n = pow2c(t1e - e1);
        float pmc = dpp_shr1(P2[1]) * f1n;
        float cs[8][2];
#pragma unroll
        for (int u = 0; u < 8; ++u) {
          float pm1 = dpp_shr1(P1[1]) * f1n;
          float pm2 = pmc;
          float c0 = fmaf(wdl[0], pm1, fmaf(W[0][4 + u], pm2, Q[4 + u] * P1[0]));
          float c1 = fmaf(wdl[1], P1[0], fmaf(W[1][3 + u], P2[0], Q[3 + u] * P1[1]));
          cs[u][0] = c0; cs[u][1] = c1;
          P2[0] = P1[0]; P2[1] = P1[1]; P1[0] = c0; P1[1] = c1;
          pmc = pm1;
        }
        if (lane == 63) {  // row-127 boundary: back-pressure, write, publish
          while (__hip_atomic_load(consp, __ATOMIC_RELAXED,
                                   __HIP_MEMORY_SCOPE_WORKGROUP) < p - 1) {}
          float* sl = shm + SLOT_OFF + (p & 1) * 12;
          *(float4*)(sl) = make_float4(cs[0][1], cs[1][1], cs[2][1], cs[3][1]);
          *(float4*)(sl + 4) = make_float4(cs[4][1], cs[5][1], cs[6][1], cs[7][1]);
          ((int*)sl)[8] = e1st;
          __hip_atomic_store(progp, p + 1, __ATOMIC_RELEASE,
                             __HIP_MEMORY_SCOPE_WORKGROUP);
        }
#pragma unroll
        for (int u = 0; u < 8; ++u) {
          *(float2*)sp = make_float2(cs[u][1], cs[u][0]);
          sp += RS;
        }
        e0 += 8;
        LOAD_A2(e0);
        float m = fmaxf(P1[0], P1[1]);
        int ex = (m > 0.f) ? ((__float_as_int(m) >> 23) - 126) : (t1e - e1);
        float sc = pow2c(-ex);
        P1[0] *= sc; P1[1] *= sc; P2[0] *= sc; P2[1] *= sc;
        e1 += ex;
        *(int2*)ep = make_int2(e1st, e1st); ep += 256;
      }
    } else {
      // ---------- ALPHA CONSUMER: rows 128..255; lane0 eats row 127 ----
      int e0 = 252 - i0;
      float* sp = aD + RS + 254 - i0;
      int* ep = aEb + i0;
      float W[2][12], Q[12];
      LOAD_A2(e0);
      float t1raw = 0.f, t2raw = 0.f;
      int eBprev = 0;
      const bool isL0 = (lane == 0);
      for (int p = 0; p < 64; ++p) {
        while (__hip_atomic_load(progp, __ATOMIC_ACQUIRE,
                                 __HIP_MEMORY_SCOPE_WORKGROUP) < p + 1) {}
        const float* sl = shm + SLOT_OFF + (p & 1) * 12;
        float4 r0 = *(const float4*)sl;
        float4 r1 = *(const float4*)(sl + 4);
        int eB = ((const int*)sl)[8];
        float scm = isL0 ? pow2c(eB - e1) : 0.f;
        float spm = isL0 ? pow2c(eBprev - e1) : 0.f;
        float B1[8];
        B1[0] = t1raw * spm;
        B1[1] = r0.x * scm; B1[2] = r0.y * scm; B1[3] = r0.z * scm;
        B1[4] = r0.w * scm; B1[5] = r1.x * scm; B1[6] = r1.y * scm;
        B1[7] = r1.z * scm;
        float B2s = t2raw * spm;
        t1raw = r1.w; t2raw = r1.z; eBprev = eB;
        const int e1st = e1;
        int td = dpp_shr1_i(e1);
        int t1e = isL0 ? eB : td;  // boundary lane adopts producer exponent
        float f1n = pow2c(t1e - e1);
        float pmc = fmaf(dpp_shr1(P2[1]), f1n, B2s);
        float cs[8][2];
#pragma unroll
        for (int u = 0; u < 8; ++u) {
          float pm1 = fmaf(dpp_shr1(P1[1]), f1n, B1[u]);
          float pm2 = pmc;
          float c0 = fmaf(wdl[0], pm1, fmaf(W[0][4 + u], pm2, Q[4 + u] * P1[0]));
          float c1 = fmaf(wdl[1], P1[0], fmaf(W[1][3 + u], P2[0], Q[3 + u] * P1[1]));
          cs[u][0] = c0; cs[u][1] = c1;
          P2[0] = P1[0]; P2[1] = P1[1]; P1[0] = c0; P1[1] = c1;
          pmc = pm1;
        }
#pragma unroll
        for (int u = 0; u < 8; ++u) {
          *(float2*)sp = make_float2(cs[u][1], cs[u][0]);
          sp += RS;
        }
        e0 += 8;
        LOAD_A2(e0);
        float m = fmaxf(P1[0], P1[1]);
        int ex = (m > 0.f) ? ((__float_as_int(m) >> 23) - 126) : (t1e - e1);
        float sc = pow2c(-ex);
        P1[0] *= sc; P1[1] *= sc; P2[0] *= sc; P2[1] *= sc;
        e1 += ex;
        *(int2*)ep = make_int2(e1st, e1st); ep += 256;
        if (isL0)
          __hip_atomic_store(consp, p + 1, __ATOMIC_RELEASE,
                             __HIP_MEMORY_SCOPE_WORKGROUP);
      }
      // ---- R12 probe: 128 LOAD-only iterations (2x the DP's 64). ----
      // asm sinks keep every loaded value live (rule #17, no DCE).
      {
        int pe = 252 - i0;
        for (int pp = 0; pp < 128; ++pp) {
          const int EBp = pe & 255;
          LOAD_A2(EBp);
#pragma unroll
          for (int x = 0; x < 12; ++x)
            asm volatile("" ::"v"(W[0][x]), "v"(W[1][x]), "v"(Q[x]));
          pe += 8;
        }
      }
      // consumer finishes last: publish alpha-done
      __threadfence();
      if (lane == 0)
        __hip_atomic_store(&flags[0], MAGIC, __ATOMIC_RELEASE,
                           __HIP_MEMORY_SCOPE_AGENT);
    }
  } else {
    if (wid == 1) {
      // ---------- BETA PRODUCER: rows 128..255; emits row 128 ----------
      if (lane == 63) P1[1] = 1.f;        // B(510,255)
      if (lane == 0) bD[510 * RS] = 1.f;  // (d=510, i=255)
      int e0 = 764 - i0;
      float* sp = bD + 509 * RS + 254 - i0;
      int* ep = bEb + i0;
      float W[2][16], Q[16];
      LOAD_B2(e0);
      for (int p = 0; p < 64; ++p) {
        const int e1st = e1;
        int t1e = dpp_shl1_i(e1);
        float f1n = pow2c(t1e - e1);
        float pmc = dpp_shl1(P2[0]) * f1n;
        float cs[8][2];
#pragma unroll
        for (int u = 0; u < 8; ++u) {
          float pm1 = dpp_shl1(P1[0]) * f1n;
          float pm2 = pmc;
          float c1 = fmaf(wdl[1], pm1, fmaf(W[1][11 - u], pm2, Q[12 - u] * P1[1]));
          float c0 = fmaf(wdl[0], P1[1], fmaf(W[0][12 - u], P2[1], Q[13 - u] * P1[0]));
          cs[u][0] = c0; cs[u][1] = c1;
          P2[0] = P1[0]; P2[1] = P1[1]; P1[0] = c0; P1[1] = c1;
          pmc = pm1;
        }
        if (lane == 0) {  // row-128 boundary: back-pressure, write, publish
          while (__hip_atomic_load(consp, __ATOMIC_RELAXED,
                                   __HIP_MEMORY_SCOPE_WORKGROUP) < p - 1) {}
          float* sl = shm + SLOT_OFF + (p & 1) * 12;
          *(float4*)(sl) = make_float4(cs[0][0], cs[1][0], cs[2][0], cs[3][0]);
          *(float4*)(sl + 4) = make_float4(cs[4][0], cs[5][0], cs[6][0], cs[7][0]);
          ((int*)sl)[8] = e1st;
          __hip_atomic_store(progp, p + 1, __ATOMIC_RELEASE,
                             __HIP_MEMORY_SCOPE_WORKGROUP);
        }
#pragma unroll
        for (int u = 0; u < 8; ++u) {
          *(float2*)sp = make_float2(cs[u][1], cs[u][0]);
          sp -= RS;
        }
        e0 -= 8;
        LOAD_B2(e0);
        float m = fmaxf(P1[0], P1[1]);
        int ex = (m > 0.f) ? ((__float_as_int(m) >> 23) - 126) : (t1e - e1);
        float sc = pow2c(-ex);
        P1[0] *= sc; P1[1] *= sc; P2[0] *= sc; P2[1] *= sc;
        e1 += ex;
        *(int2*)ep = make_int2(e1st, e1st); ep += 256;
      }
    } else {
      // ---------- BETA CONSUMER: rows 0..127; lane63 eats row 128 ------
      int e0 = 764 - i0;
      float* sp = bD + 509 * RS + 254 - i0;
      int* ep = bEb + i0;
      float W[2][16], Q[16];
      LOAD_B2(e0);
      float t1raw = 0.f, t2raw = 0.f;
      int eBprev = 0;
      const bool isT = (lane == 63);
      for (int p = 0; p < 64; ++p) {
        while (__hip_atomic_load(progp, __ATOMIC_ACQUIRE,
                                 __HIP_MEMORY_SCOPE_WORKGROUP) < p + 1) {}
        const float* sl = shm + SLOT_OFF + (p & 1) * 12;
        float4 r0 = *(const float4*)sl;
        float4 r1 = *(const float4*)(sl + 4);
        int eB = ((const int*)sl)[8];
        float scm = isT ? pow2c(eB - e1) : 0.f;
        float spm = isT ? pow2c(eBprev - e1) : 0.f;
        float B1[8];
        B1[0] = t1raw * spm;
        B1[1] = r0.x * scm; B1[2] = r0.y * scm; B1[3] = r0.z * scm;
        B1[4] = r0.w * scm; B1[5] = r1.x * scm; B1[6] = r1.y * scm;
        B1[7] = r1.z * scm;
        float B2s = t2raw * spm;
        t1raw = r1.w; t2raw = r1.z; eBprev = eB;
        const int e1st = e1;
        int td = dpp_shl1_i(e1);
        int t1e = isT ? eB : td;  // boundary lane adopts producer exponent
        float f1n = pow2c(t1e - e1);
        float pmc = fmaf(dpp_shl1(P2[0]), f1n, B2s);
        float cs[8][2];
#pragma unroll
        for (int u = 0; u < 8; ++u) {
          float pm1 = fmaf(dpp_shl1(P1[0]), f1n, B1[u]);
          float pm2 = pmc;
          float c1 = fmaf(wdl[1], pm1, fmaf(W[1][11 - u], pm2, Q[12 - u] * P1[1]));
          float c0 = fmaf(wdl[0], P1[1], fmaf(W[0][12 - u], P2[1], Q[13 - u] * P1[0]));
          cs[u][0] = c0; cs[u][1] = c1;
          P2[0] = P1[0]; P2[1] = P1[1]; P1[0] = c0; P1[1] = c1;
          pmc = pm1;
        }
#pragma unroll
        for (int u = 0; u < 8; ++u) {
          *(float2*)sp = make_float2(cs[u][1], cs[u][0]);
          sp -= RS;
        }
        e0 -= 8;
        LOAD_B2(e0);
        float m = fmaxf(P1[0], P1[1]);
        int ex = (m > 0.f) ? ((__float_as_int(m) >> 23) - 126) : (t1e - e1);
        float sc = pow2c(-ex);
        P1[0] *= sc; P1[1] *= sc; P2[0] *= sc; P2[1] *= sc;
        e1 += ex;
        *(int2*)ep = make_int2(e1st, e1st); ep += 256;
        if (isT)
          __hip_atomic_store(consp, p + 1, __ATOMIC_RELEASE,
                             __HIP_MEMORY_SCOPE_WORKGROUP);
      }
      // consumer finishes last: publish beta-done
      __threadfence();
      if (lane == 0)
        __hip_atomic_store(&flags[1], MAGIC, __ATOMIC_RELEASE,
                           __HIP_MEMORY_SCOPE_AGENT);
    }
  }
}

// k_red: block b reduces diagonals 4b..4b+3 into LDS bins, flushes into
// S slice (b & 7); ticket winner sums the 8 slices and writes out.
// Exponent arrays are per-row (R10): aEb[p*256 + i], bEb[p*256 + i].
__global__ __launch_bounds__(256) void k_red(const int* __restrict__ ar,
                                             const int* __restrict__ en,
                                             const float* __restrict__ wts,
                                             const float* __restrict__ aD,
                                             const float* __restrict__ bD,
                                             const int* __restrict__ aEb,
                                             const int* __restrict__ bEb,
                                             float* __restrict__ S,
                                             unsigned* __restrict__ flags,
                                             float* __restrict__ out) {
  const int tid = threadIdx.x;
  __shared__ float bins[NCLS];
  __shared__ int ctl;
  for (int c = tid; c < NCLS; c += 256) bins[c] = 0.f;
  __syncthreads();
  const float M = __logf(aD[510 * RS]) +
                  (float)aEb[63 * 256 + 255] * LN2F + 16.0f;
  const int j = tid;
  const int e = en[j];
#pragma unroll
  for (int u = 0; u < 4; ++u) {
    const int d = (int)blockIdx.x * 4 + u;
    if (d <= 510) {
      const int i = d - j;
      if (i >= 0 && i <= 255) {
        const float bM = bD[d * RS + 255 - i];
        if (bM > 0.f) {
          const int bEx =
              (d == 510) ? 0 : bEb[((509 - d) >> 3) * 256 + i];
          const float lb = __logf(bM) + (float)bEx * LN2F - M;
          const int a = ar[i];
          if (i >= 1) {
            float aM = aD[(d - 1) * RS + 256 - i];
            if (aM > 0.f) {
              int eA = (d == 1) ? 0 : aEb[((d - 2) >> 3) * 256 + (i - 1)];
              float L = __logf(aM) + (float)eA * LN2F + lb;
              atomicAdd(&bins[1 + a], __expf(fminf(L, 0.f)));
            }
          }
          if (j >= 1) {
            float aM = aD[(d - 1) * RS + 255 - i];
            if (aM > 0.f) {
              int eA = (d == 1) ? 0 : aEb[((d - 2) >> 3) * 256 + i];
              float L = __logf(aM) + (float)eA * LN2F + lb;
              atomicAdd(&bins[26 + e], __expf(fminf(L, 0.f)));
            }
            if (i >= 1) {
              float aM2 = aD[(d - 2) * RS + 256 - i];
              if (aM2 > 0.f) {
                int eA2 = (d == 2) ? 0 : aEb[((d - 3) >> 3) * 256 + (i - 1)];
                float L2 = __logf(aM2) + (float)eA2 * LN2F + lb;
                atomicAdd(&bins[51 + 25 * a + e], __expf(fminf(L2, 0.f)));
              }
            }
          }
        }
      }
    }
  }
  __syncthreads();
  float* Ss = S + (blockIdx.x & (NSLICE - 1)) * NCLS;
  for (int c = tid; c < NCLS; c += 256)
    if (bins[c] != 0.f) atomicAdd(&Ss[c], bins[c]);
  __syncthreads();
  if (tid == 0) {
    unsigned n = __hip_atomic_fetch_add(&flags[2], 1u, __ATOMIC_ACQ_REL,
                                        __HIP_MEMORY_SCOPE_AGENT);
    ctl = ((n & 127u) == 127u);
  }
  __syncthreads();
  if (ctl) {
    for (int c = tid; c < NCLS; c += 256) {
      float s = 0.f;
#pragma unroll
      for (int q = 0; q < NSLICE; ++q)
        s += __hip_atomic_load(&S[q * NCLS + c], __ATOMIC_RELAXED,
                               __HIP_MEMORY_SCOPE_AGENT);
      out[c] = (c != 0 && s > 0.f) ? (wts[c] + M + __logf(s)) : NEG_SENTINEL;
    }
  }
}

extern "C" void kernel_launch(void* const* d_in, const int* in_sizes, int n_in,
                              void* d_out, int out_size, void* d_ws, size_t ws_size,
                              hipStream_t stream) {
  const int* ar = (const int*)d_in[0];
  const int* en = (const int*)d_in[1];
  const float* wts = (const float*)d_in[2];
  float* aD = (float*)d_ws;                  // 514 diag-rows x 256, i-indexed
  float* bDraw = aD + 514 * RS;              // 514 diag-rows x 256
  float* bD = bDraw + 2 * RS;                // beta rows -2..510
  int* aEb = (int*)(bDraw + 514 * RS);       // 64 PROCs x 256 rows
  int* bEb = aEb + 64 * 256;
  float* S = (float*)(bEb + 64 * 256);       // 8 sliced copies x 676 (atomic)
  unsigned* flags = (unsigned*)(S + NSLICE * NCLS);  // [0,1]=DP, [2]=ticket
  k_dp<<<2, 256, 0, stream>>>(ar, en, wts, aD, bD, aEb, bEb, S, flags);
  k_red<<<128, 256, 0, stream>>>(ar, en, wts, aD, bD, aEb, bEb, S, flags,
                                 (float*)d_out);
}

// Round 13
// 107.579 us; speedup vs baseline: 1.0575x; 1.0575x over previous
//
#include <hip/hip_runtime.h>
#include <math.h>

#define NCLS 676
#define NEG_SENTINEL -3.0e38f  // finite stand-in for -inf (checker: inf-inf=nan)
#define LN2F 0.6931471805599453f
#define JPAD 768     // padded j-axis of weight tables (R2: 768 is conflict-optimal)
#define RS 256       // aD/bD diag-row stride, i-indexed (R4): [d*RS + 255 - i]
#define QIP_OFF 692  // qip base (16-float front guard after pw)
#define WSE_OFF (QIP_OFF + JPAD)             // 1460
#define CTL_PROG 20692                       // producer progress (int)
#define CTL_CONS 20693                       // consumer progress (int)
#define SLOT_OFF 20696                       // 2 slots x 12 floats, 16B aligned
#define SHM_TOT 20720                        // 82.9 KB -> 1 block/CU
#define MAGIC 0x13579BDFu
#define NSLICE 8     // sliced S copies: 8x fewer atomics per address

__device__ __forceinline__ float dpp_shr1(float x) {  // lane n <- n-1, lane0 0
  return __int_as_float(
      __builtin_amdgcn_update_dpp(0, __float_as_int(x), 0x138, 0xF, 0xF, false));
}
__device__ __forceinline__ float dpp_shl1(float x) {  // lane n <- n+1, lane63 0
  return __int_as_float(
      __builtin_amdgcn_update_dpp(0, __float_as_int(x), 0x130, 0xF, 0xF, false));
}
__device__ __forceinline__ int dpp_shr1_i(int x) {
  return __builtin_amdgcn_update_dpp(0, x, 0x138, 0xF, 0xF, false);
}
__device__ __forceinline__ int dpp_shl1_i(int x) {
  return __builtin_amdgcn_update_dpp(0, x, 0x130, 0xF, 0xF, false);
}
__device__ __forceinline__ float pow2c(int d) {  // exact 2^d, clamped
  d = min(max(d, -126), 126);
  return __int_as_float((d + 127) << 23);
}

// R13: FUSED + INCREMENTAL REDUCE. R12's probe priced the DP's LDS loads at
// ~210cy/PROC (ds_read_b64 at m134 throughput) -- loads fine, residual
// ~1100cy/PROC resists everything (7 structural nulls). DP is accepted as a
// ~40us floor; this round recovers the STRUCTURAL overhead instead:
// split-kernel reduce + 2nd launch + dispatch-edge drain ~= 17-22us of the
// total vs ~12.7 fused. One kernel: blocks 0/1 = DP (R10 2-wave pipeline),
// publishing progress counters every 8 PROCs (threadfence + agent-release,
// the proven R1 pattern x8): flags[3]=aP,[4]=aC,[5]=bP,[6]=bC (chunk 1..8).
// Blocks 2..129 = workers: wait for the chunks covering their 4 diagonals
// (alpha <= dmax-1, beta >= dmin), then do loads+logf WITHOUT M (M-free
// log-sums in registers) DURING the DP tail; after flags[0,1]==MAGIC only
// ~12 exp + LDS-bin atomics + sliced-S flush remain. Ticket winner writes
// out. flags[0..6] zeroed by a hipMemsetAsync node before the kernel (no
// init race, no poison assumption).
// Alpha chunk c completes diags 1..64c (d=0 seeded pre-PROC0, drained by
// chunk 1); beta chunk c completes diags >= 510-64c (d=510 seed likewise).
__global__ __launch_bounds__(256, 1) void k_fused(const int* __restrict__ ar,
                                                  const int* __restrict__ en,
                                                  const float* __restrict__ wts,
                                                  float* __restrict__ aD,
                                                  float* __restrict__ bD,
                                                  int* __restrict__ aEb,
                                                  int* __restrict__ bEb,
                                                  float* __restrict__ S,
                                                  unsigned* __restrict__ flags,
                                                  float* __restrict__ out) {
  const int tid = threadIdx.x;
  __shared__ alignas(16) float shm[SHM_TOT];

  if (blockIdx.x >= 2) {
    // ================= worker block: incremental reduce =================
    float* bins = shm;  // 676 floats
    for (int c = tid; c < NCLS; c += 256) bins[c] = 0.f;
    __syncthreads();
    const int dbase = 4 * ((int)blockIdx.x - 2);
    const int dmaxv = min(dbase + 3, 510);
    const unsigned cA = (unsigned)max(1, min(8, (dmaxv - 1 + 63) / 64));
    const unsigned cB = (unsigned)max(1, min(8, (510 - dbase + 63) / 64));
    if (tid == 0) {
      while (__hip_atomic_load(&flags[3], __ATOMIC_RELAXED,
                               __HIP_MEMORY_SCOPE_AGENT) < cA ||
             __hip_atomic_load(&flags[4], __ATOMIC_RELAXED,
                               __HIP_MEMORY_SCOPE_AGENT) < cA ||
             __hip_atomic_load(&flags[5], __ATOMIC_RELAXED,
                               __HIP_MEMORY_SCOPE_AGENT) < cB ||
             __hip_atomic_load(&flags[6], __ATOMIC_RELAXED,
                               __HIP_MEMORY_SCOPE_AGENT) < cB)
        __builtin_amdgcn_s_sleep(8);
      (void)__hip_atomic_load(&flags[3], __ATOMIC_ACQUIRE,
                              __HIP_MEMORY_SCOPE_AGENT);  // inv L1/L2
    }
    __syncthreads();
    const int j = tid;
    const int e = en[j];
    // ---- phase 1: loads + logf, NO M (M-free log-sums in registers) ----
    float S1[4], S2[4], S3[4];
    int C1[4], C3[4];
#pragma unroll
    for (int u = 0; u < 4; ++u) {
      S1[u] = NEG_SENTINEL; S2[u] = NEG_SENTINEL; S3[u] = NEG_SENTINEL;
      C1[u] = 0; C3[u] = 0;
      const int d = dbase + u;
      if (d <= 510) {
        const int i = d - j;
        if (i >= 0 && i <= 255) {
          const float bM = bD[d * RS + 255 - i];
          if (bM > 0.f) {
            const int bEx =
                (d == 510) ? 0 : bEb[((509 - d) >> 3) * 256 + i];
            const float lb = __logf(bM) + (float)bEx * LN2F;
            const int a = ar[i];
            C1[u] = 1 + a;
            C3[u] = 51 + 25 * a + e;
            if (i >= 1) {
              float aM = aD[(d - 1) * RS + 256 - i];
              if (aM > 0.f) {
                int eA = (d == 1) ? 0 : aEb[((d - 2) >> 3) * 256 + (i - 1)];
                S1[u] = __logf(aM) + (float)eA * LN2F + lb;
              }
            }
            if (j >= 1) {
              float aM = aD[(d - 1) * RS + 255 - i];
              if (aM > 0.f) {
                int eA = (d == 1) ? 0 : aEb[((d - 2) >> 3) * 256 + i];
                S2[u] = __logf(aM) + (float)eA * LN2F + lb;
              }
              if (i >= 1) {
                float aM2 = aD[(d - 2) * RS + 256 - i];
                if (aM2 > 0.f) {
                  int eA2 = (d == 2) ? 0 : aEb[((d - 3) >> 3) * 256 + (i - 1)];
                  S3[u] = __logf(aM2) + (float)eA2 * LN2F + lb;
                }
              }
            }
          }
        }
      }
    }
    // ---- phase 2: wait both DP done -> M known; exp + bin atomics ----
    if (tid == 0) {
      while (__hip_atomic_load(&flags[0], __ATOMIC_RELAXED,
                               __HIP_MEMORY_SCOPE_AGENT) != MAGIC ||
             __hip_atomic_load(&flags[1], __ATOMIC_RELAXED,
                               __HIP_MEMORY_SCOPE_AGENT) != MAGIC)
        __builtin_amdgcn_s_sleep(8);
      (void)__hip_atomic_load(&flags[0], __ATOMIC_ACQUIRE,
                              __HIP_MEMORY_SCOPE_AGENT);
    }
    __syncthreads();
    const float M = __logf(aD[510 * RS]) +
                    (float)aEb[63 * 256 + 255] * LN2F + 16.0f;
#pragma unroll
    for (int u = 0; u < 4; ++u) {
      if (S1[u] > -1.0e30f)
        atomicAdd(&bins[C1[u]], __expf(fminf(S1[u] - M, 0.f)));
      if (S2[u] > -1.0e30f)
        atomicAdd(&bins[26 + e], __expf(fminf(S2[u] - M, 0.f)));
      if (S3[u] > -1.0e30f)
        atomicAdd(&bins[C3[u]], __expf(fminf(S3[u] - M, 0.f)));
    }
    __syncthreads();
    float* Ss = S + ((int)blockIdx.x & (NSLICE - 1)) * NCLS;
    for (int c = tid; c < NCLS; c += 256)
      if (bins[c] != 0.f) atomicAdd(&Ss[c], bins[c]);
    // ---- ticket; last of the 128 workers writes `out` ----
    __syncthreads();
    __shared__ int ctlw;
    if (tid == 0) {
      unsigned n = __hip_atomic_fetch_add(&flags[2], 1u, __ATOMIC_ACQ_REL,
                                          __HIP_MEMORY_SCOPE_AGENT);
      ctlw = ((n & 127u) == 127u);
    }
    __syncthreads();
    if (ctlw) {
      for (int c = tid; c < NCLS; c += 256) {
        float s = 0.f;
#pragma unroll
        for (int q = 0; q < NSLICE; ++q)
          s += __hip_atomic_load(&S[q * NCLS + c], __ATOMIC_RELAXED,
                                 __HIP_MEMORY_SCOPE_AGENT);
        out[c] = (c != 0 && s > 0.f) ? (wts[c] + M + __logf(s)) : NEG_SENTINEL;
      }
    }
    return;
  }

  // ================= DP blocks 0 (alpha) / 1 (beta) ====================
  float* pw = shm;  // exp(weights), 676
  int* progp = (int*)(shm + CTL_PROG);
  int* consp = (int*)(shm + CTL_CONS);
  for (int c = tid; c < NCLS; c += 256) pw[c] = __expf(wts[c]);
  {  // zero guards + tables + ctl area (16B aligned at 676*4)
    float4* z = (float4*)(shm + NCLS);
    const int nz = (SHM_TOT - NCLS) / 4;
    for (int t = tid; t < nz; t += 256) z[t] = make_float4(0.f, 0.f, 0.f, 0.f);
  }
  if (tid == 0) { *progp = 0; *consp = 0; }
  if (blockIdx.x == 0)
    for (int c = tid; c < NSLICE * NCLS; c += 256) S[c] = 0.f;
  __syncthreads();
  {
    int j = tid;  // 256 threads: one column each
    int ee = en[j];
    shm[QIP_OFF + 255 + j] = pw[26 + ee];
#pragma unroll
    for (int a = 0; a < 25; ++a)
      shm[WSE_OFF + a * JPAD + 255 + j] = pw[51 + 25 * a + ee];
  }
  __syncthreads();
  const int wid = tid >> 6;
  const int lane = tid & 63;
  if (wid >= 2) return;  // waves 2-3 done after table build

  const int i0 = 2 * lane + 128 * wid;  // this lane's 2 rows: i0, i0+1
  float wdl[2];
  int roff[2];  // integer offsets into shm (addrspace-safe)
#pragma unroll
  for (int k = 0; k < 2; ++k) {
    int a = ar[i0 + k];
    wdl[k] = pw[1 + a];
    roff[k] = WSE_OFF + a * JPAD;
  }
  float P1[2] = {0.f, 0.f};
  float P2[2] = {0.f, 0.f};
  int e1 = 0;

// 12-float window loads via direct shm indexing (8B-aligned: offsets even)
#define LOAD_A2(EB)                                                        \
  {                                                                        \
    _Pragma("unroll") for (int k = 0; k < 2; ++k) {                        \
      const int bo = roff[k] + (EB);                                       \
      float2 va = *(const float2*)&shm[bo];                                \
      float2 vb = *(const float2*)&shm[bo + 2];                            \
      float2 vc = *(const float2*)&shm[bo + 4];                            \
      float2 vd = *(const float2*)&shm[bo + 6];                            \
      float2 ve = *(const float2*)&shm[bo + 8];                            \
      float2 vf = *(const float2*)&shm[bo + 10];                           \
      W[k][0] = va.x; W[k][1] = va.y; W[k][2] = vb.x; W[k][3] = vb.y;      \
      W[k][4] = vc.x; W[k][5] = vc.y; W[k][6] = vd.x; W[k][7] = vd.y;      \
      W[k][8] = ve.x; W[k][9] = ve.y; W[k][10] = vf.x; W[k][11] = vf.y;    \
    }                                                                      \
    const int qo = QIP_OFF + (EB);                                         \
    float2 qa = *(const float2*)&shm[qo];                                  \
    float2 qb = *(const float2*)&shm[qo + 2];                              \
    float2 qc = *(const float2*)&shm[qo + 4];                              \
    float2 qd = *(const float2*)&shm[qo + 6];                              \
    float2 qe = *(const float2*)&shm[qo + 8];                              \
    float2 qf = *(const float2*)&shm[qo + 10];                             \
    Q[0] = qa.x; Q[1] = qa.y; Q[2] = qb.x; Q[3] = qb.y; Q[4] = qc.x;       \
    Q[5] = qc.y; Q[6] = qd.x; Q[7] = qd.y; Q[8] = qe.x; Q[9] = qe.y;       \
    Q[10] = qf.x; Q[11] = qf.y;                                            \
  }

// 16-float window loads (beta), direct shm indexing
#define LOAD_B2(EB)                                                        \
  {                                                                        \
    _Pragma("unroll") for (int k = 0; k < 2; ++k) {                        \
      const int bo = roff[k] + (EB);                                       \
      float2 va = *(const float2*)&shm[bo];                                \
      float2 vb = *(const float2*)&shm[bo + 2];                            \
      float2 vc = *(const float2*)&shm[bo + 4];                            \
      float2 vd = *(const float2*)&shm[bo + 6];                            \
      float2 ve = *(const float2*)&shm[bo + 8];                            \
      float2 vf = *(const float2*)&shm[bo + 10];                           \
      float2 vg = *(const float2*)&shm[bo + 12];                           \
      float2 vh = *(const float2*)&shm[bo + 14];                           \
      W[k][0] = va.x; W[k][1] = va.y; W[k][2] = vb.x; W[k][3] = vb.y;      \
      W[k][4] = vc.x; W[k][5] = vc.y; W[k][6] = vd.x; W[k][7] = vd.y;      \
      W[k][8] = ve.x; W[k][9] = ve.y; W[k][10] = vf.x; W[k][11] = vf.y;    \
      W[k][12] = vg.x; W[k][13] = vg.y; W[k][14] = vh.x; W[k][15] = vh.y;  \
    }                                                                      \
    const int qo = QIP_OFF + (EB);                                         \
    float2 qa = *(const float2*)&shm[qo];                                  \
    float2 qb = *(const float2*)&shm[qo + 2];                              \
    float2 qc = *(const float2*)&shm[qo + 4];                              \
    float2 qd = *(const float2*)&shm[qo + 6];                              \
    float2 qe = *(const float2*)&shm[qo + 8];                              \
    float2 qf = *(const float2*)&shm[qo + 10];                             \
    float2 qg = *(const float2*)&shm[qo + 12];                             \
    float2 qh = *(const float2*)&shm[qo + 14];                             \
    Q[0] = qa.x; Q[1] = qa.y; Q[2] = qb.x; Q[3] = qb.y; Q[4] = qc.x;       \
    Q[5] = qc.y; Q[6] = qd.x; Q[7] = qd.y; Q[8] = qe.x; Q[9] = qe.y;       \
    Q[10] = qf.x; Q[11] = qf.y; Q[12] = qg.x; Q[13] = qg.y; Q[14] = qh.x;  \
    Q[15] = qh.y;                                                          \
  }

// chunk publish: every 8 PROCs, drain stores then release counter FID
#define PUBLISH(FID)                                                       \
  if ((p & 7) == 7) {                                                      \
    __threadfence();                                                       \
    if (lane == 0)                                                         \
      __hip_atomic_store(&flags[FID], (unsigned)((p >> 3) + 1),            \
                         __ATOMIC_RELEASE, __HIP_MEMORY_SCOPE_AGENT);      \
  }

  if (blockIdx.x == 0) {
    if (wid == 0) {
      // ---------- ALPHA PRODUCER: rows 0..127; emits row 127 ----------
      if (lane == 0) { P1[0] = 1.f; aD[255] = 1.f; }  // A(0,0)
      int e0 = 252 - i0;
      float* sp = aD + RS + 254 - i0;
      int* ep = aEb + i0;
      float W[2][12], Q[12];
      LOAD_A2(e0);
      for (int p = 0; p < 64; ++p) {
        const int e1st = e1;
        int t1e = dpp_shr1_i(e1);
        float f1n = pow2c(t1e - e1);
        float pmc = dpp_shr1(P2[1]) * f1n;
        float cs[8][2];
#pragma unroll
        for (int u = 0; u < 8; ++u) {
          float pm1 = dpp_shr1(P1[1]) * f1n;
          float pm2 = pmc;
          float c0 = fmaf(wdl[0], pm1, fmaf(W[0][4 + u], pm2, Q[4 + u] * P1[0]));
          float c1 = fmaf(wdl[1], P1[0], fmaf(W[1][3 + u], P2[0], Q[3 + u] * P1[1]));
          cs[u][0] = c0; cs[u][1] = c1;
          P2[0] = P1[0]; P2[1] = P1[1]; P1[0] = c0; P1[1] = c1;
          pmc = pm1;
        }
        if (lane == 63) {  // row-127 boundary: back-pressure, write, publish
          while (__hip_atomic_load(consp, __ATOMIC_RELAXED,
                                   __HIP_MEMORY_SCOPE_WORKGROUP) < p - 1) {}
          float* sl = shm + SLOT_OFF + (p & 1) * 12;
          *(float4*)(sl) = make_float4(cs[0][1], cs[1][1], cs[2][1], cs[3][1]);
          *(float4*)(sl + 4) = make_float4(cs[4][1], cs[5][1], cs[6][1], cs[7][1]);
          ((int*)sl)[8] = e1st;
          __hip_atomic_store(progp, p + 1, __ATOMIC_RELEASE,
                             __HIP_MEMORY_SCOPE_WORKGROUP);
        }
#pragma unroll
        for (int u = 0; u < 8; ++u) {
          *(float2*)sp = make_float2(cs[u][1], cs[u][0]);
          sp += RS;
        }
        e0 += 8;
        LOAD_A2(e0);
        float m = fmaxf(P1[0], P1[1]);
        int ex = (m > 0.f) ? ((__float_as_int(m) >> 23) - 126) : (t1e - e1);
        float sc = pow2c(-ex);
        P1[0] *= sc; P1[1] *= sc; P2[0] *= sc; P2[1] *= sc;
        e1 += ex;
        *(int2*)ep = make_int2(e1st, e1st); ep += 256;
        PUBLISH(3)  // aP
      }
    } else {
      // ---------- ALPHA CONSUMER: rows 128..255; lane0 eats row 127 ----
      int e0 = 252 - i0;
      float* sp = aD + RS + 254 - i0;
      int* ep = aEb + i0;
      float W[2][12], Q[12];
      LOAD_A2(e0);
      float t1raw = 0.f, t2raw = 0.f;
      int eBprev = 0;
      const bool isL0 = (lane == 0);
      for (int p = 0; p < 64; ++p) {
        while (__hip_atomic_load(progp, __ATOMIC_ACQUIRE,
                                 __HIP_MEMORY_SCOPE_WORKGROUP) < p + 1) {}
        const float* sl = shm + SLOT_OFF + (p & 1) * 12;
        float4 r0 = *(const float4*)sl;
        float4 r1 = *(const float4*)(sl + 4);
        int eB = ((const int*)sl)[8];
        float scm = isL0 ? pow2c(eB - e1) : 0.f;
        float spm = isL0 ? pow2c(eBprev - e1) : 0.f;
        float B1[8];
        B1[0] = t1raw * spm;
        B1[1] = r0.x * scm; B1[2] = r0.y * scm; B1[3] = r0.z * scm;
        B1[4] = r0.w * scm; B1[5] = r1.x * scm; B1[6] = r1.y * scm;
        B1[7] = r1.z * scm;
        float B2s = t2raw * spm;
        t1raw = r1.w; t2raw = r1.z; eBprev = eB;
        const int e1st = e1;
        int td = dpp_shr1_i(e1);
        int t1e = isL0 ? eB : td;  // boundary lane adopts producer exponent
        float f1n = pow2c(t1e - e1);
        float pmc = fmaf(dpp_shr1(P2[1]), f1n, B2s);
        float cs[8][2];
#pragma unroll
        for (int u = 0; u < 8; ++u) {
          float pm1 = fmaf(dpp_shr1(P1[1]), f1n, B1[u]);
          float pm2 = pmc;
          float c0 = fmaf(wdl[0], pm1, fmaf(W[0][4 + u], pm2, Q[4 + u] * P1[0]));
          float c1 = fmaf(wdl[1], P1[0], fmaf(W[1][3 + u], P2[0], Q[3 + u] * P1[1]));
          cs[u][0] = c0; cs[u][1] = c1;
          P2[0] = P1[0]; P2[1] = P1[1]; P1[0] = c0; P1[1] = c1;
          pmc = pm1;
        }
#pragma unroll
        for (int u = 0; u < 8; ++u) {
          *(float2*)sp = make_float2(cs[u][1], cs[u][0]);
          sp += RS;
        }
        e0 += 8;
        LOAD_A2(e0);
        float m = fmaxf(P1[0], P1[1]);
        int ex = (m > 0.f) ? ((__float_as_int(m) >> 23) - 126) : (t1e - e1);
        float sc = pow2c(-ex);
        P1[0] *= sc; P1[1] *= sc; P2[0] *= sc; P2[1] *= sc;
        e1 += ex;
        *(int2*)ep = make_int2(e1st, e1st); ep += 256;
        if (isL0)
          __hip_atomic_store(consp, p + 1, __ATOMIC_RELEASE,
                             __HIP_MEMORY_SCOPE_WORKGROUP);
        PUBLISH(4)  // aC
      }
      // consumer finishes last: publish alpha-done
      __threadfence();
      if (lane == 0)
        __hip_atomic_store(&flags[0], MAGIC, __ATOMIC_RELEASE,
                           __HIP_MEMORY_SCOPE_AGENT);
    }
  } else {
    if (wid == 1) {
      // ---------- BETA PRODUCER: rows 128..255; emits row 128 ----------
      if (lane == 63) P1[1] = 1.f;        // B(510,255)
      if (lane == 0) bD[510 * RS] = 1.f;  // (d=510, i=255)
      int e0 = 764 - i0;
      float* sp = bD + 509 * RS + 254 - i0;
      int* ep = bEb + i0;
      float W[2][16], Q[16];
      LOAD_B2(e0);
      for (int p = 0; p < 64; ++p) {
        const int e1st = e1;
        int t1e = dpp_shl1_i(e1);
        float f1n = pow2c(t1e - e1);
        float pmc = dpp_shl1(P2[0]) * f1n;
        float cs[8][2];
#pragma unroll
        for (int u = 0; u < 8; ++u) {
          float pm1 = dpp_shl1(P1[0]) * f1n;
          float pm2 = pmc;
          float c1 = fmaf(wdl[1], pm1, fmaf(W[1][11 - u], pm2, Q[12 - u] * P1[1]));
          float c0 = fmaf(wdl[0], P1[1], fmaf(W[0][12 - u], P2[1], Q[13 - u] * P1[0]));
          cs[u][0] = c0; cs[u][1] = c1;
          P2[0] = P1[0]; P2[1] = P1[1]; P1[0] = c0; P1[1] = c1;
          pmc = pm1;
        }
        if (lane == 0) {  // row-128 boundary: back-pressure, write, publish
          while (__hip_atomic_load(consp, __ATOMIC_RELAXED,
                                   __HIP_MEMORY_SCOPE_WORKGROUP) < p - 1) {}
          float* sl = shm + SLOT_OFF + (p & 1) * 12;
          *(float4*)(sl) = make_float4(cs[0][0], cs[1][0], cs[2][0], cs[3][0]);
          *(float4*)(sl + 4) = make_float4(cs[4][0], cs[5][0], cs[6][0], cs[7][0]);
          ((int*)sl)[8] = e1st;
          __hip_atomic_store(progp, p + 1, __ATOMIC_RELEASE,
                             __HIP_MEMORY_SCOPE_WORKGROUP);
        }
#pragma unroll
        for (int u = 0; u < 8; ++u) {
          *(float2*)sp = make_float2(cs[u][1], cs[u][0]);
          sp -= RS;
        }
        e0 -= 8;
        LOAD_B2(e0);
        float m = fmaxf(P1[0], P1[1]);
        int ex = (m > 0.f) ? ((__float_as_int(m) >> 23) - 126) : (t1e - e1);
        float sc = pow2c(-ex);
        P1[0] *= sc; P1[1] *= sc; P2[0] *= sc; P2[1] *= sc;
        e1 += ex;
        *(int2*)ep = make_int2(e1st, e1st); ep += 256;
        PUBLISH(5)  // bP
      }
    } else {
      // ---------- BETA CONSUMER: rows 0..127; lane63 eats row 128 ------
      int e0 = 764 - i0;
      float* sp = bD + 509 * RS + 254 - i0;
      int* ep = bEb + i0;
      float W[2][16], Q[16];
      LOAD_B2(e0);
      float t1raw = 0.f, t2raw = 0.f;
      int eBprev = 0;
      const bool isT = (lane == 63);
      for (int p = 0; p < 64; ++p) {
        while (__hip_atomic_load(progp, __ATOMIC_ACQUIRE,
                                 __HIP_MEMORY_SCOPE_WORKGROUP) < p + 1) {}
        const float* sl = shm + SLOT_OFF + (p & 1) * 12;
        float4 r0 = *(const float4*)sl;
        float4 r1 = *(const float4*)(sl + 4);
        int eB = ((const int*)sl)[8];
        float scm = isT ? pow2c(eB - e1) : 0.f;
        float spm = isT ? pow2c(eBprev - e1) : 0.f;
        float B1[8];
        B1[0] = t1raw * spm;
        B1[1] = r0.x * scm; B1[2] = r0.y * scm; B1[3] = r0.z * scm;
        B1[4] = r0.w * scm; B1[5] = r1.x * scm; B1[6] = r1.y * scm;
        B1[7] = r1.z * scm;
        float B2s = t2raw * spm;
        t1raw = r1.w; t2raw = r1.z; eBprev = eB;
        const int e1st = e1;
        int td = dpp_shl1_i(e1);
        int t1e = isT ? eB : td;  // boundary lane adopts producer exponent
        float f1n = pow2c(t1e - e1);
        float pmc = fmaf(dpp_shl1(P2[0]), f1n, B2s);
        float cs[8][2];
#pragma unroll
        for (int u = 0; u < 8; ++u) {
          float pm1 = fmaf(dpp_shl1(P1[0]), f1n, B1[u]);
          float pm2 = pmc;
          float c1 = fmaf(wdl[1], pm1, fmaf(W[1][11 - u], pm2, Q[12 - u] * P1[1]));
          float c0 = fmaf(wdl[0], P1[1], fmaf(W[0][12 - u], P2[1], Q[13 - u] * P1[0]));
          cs[u][0] = c0; cs[u][1] = c1;
          P2[0] = P1[0]; P2[1] = P1[1]; P1[0] = c0; P1[1] = c1;
          pmc = pm1;
        }
#pragma unroll
        for (int u = 0; u < 8; ++u) {
          *(float2*)sp = make_float2(cs[u][1], cs[u][0]);
          sp -= RS;
        }
        e0 -= 8;
        LOAD_B2(e0);
        float m = fmaxf(P1[0], P1[1]);
        int ex = (m > 0.f) ? ((__float_as_int(m) >> 23) - 126) : (t1e - e1);
        float sc = pow2c(-ex);
        P1[0] *= sc; P1[1] *= sc; P2[0] *= sc; P2[1] *= sc;
        e1 += ex;
        *(int2*)ep = make_int2(e1st, e1st); ep += 256;
        if (isT)
          __hip_atomic_store(consp, p + 1, __ATOMIC_RELEASE,
                             __HIP_MEMORY_SCOPE_WORKGROUP);
        PUBLISH(6)  // bC
      }
      // consumer finishes last: publish beta-done
      __threadfence();
      if (lane == 0)
        __hip_atomic_store(&flags[1], MAGIC, __ATOMIC_RELEASE,
                           __HIP_MEMORY_SCOPE_AGENT);
    }
  }
}

extern "C" void kernel_launch(void* const* d_in, const int* in_sizes, int n_in,
                              void* d_out, int out_size, void* d_ws, size_t ws_size,
                              hipStream_t stream) {
  const int* ar = (const int*)d_in[0];
  const int* en = (const int*)d_in[1];
  const float* wts = (const float*)d_in[2];
  float* aD = (float*)d_ws;                  // 514 diag-rows x 256, i-indexed
  float* bDraw = aD + 514 * RS;              // 514 diag-rows x 256
  float* bD = bDraw + 2 * RS;                // beta rows -2..510
  int* aEb = (int*)(bDraw + 514 * RS);       // 64 PROCs x 256 rows
  int* bEb = aEb + 64 * 256;
  float* S = (float*)(bEb + 64 * 256);       // 8 sliced copies x 676 (atomic)
  unsigned* flags = (unsigned*)(S + NSLICE * NCLS);
  // flags: [0]=alpha MAGIC, [1]=beta MAGIC, [2]=ticket, [3..6]=aP,aC,bP,bC
  hipMemsetAsync((void*)flags, 0, 7 * sizeof(unsigned), stream);
  k_fused<<<130, 256, 0, stream>>>(ar, en, wts, aD, bD, aEb, bEb, S, flags,
                                   (float*)d_out);
}